// Round 6
// baseline (184.631 us; speedup 1.0000x reference)
//
#include <hip/hip_runtime.h>
#include <hip/hip_bf16.h>

using bf16 = __hip_bfloat16;
typedef __attribute__((ext_vector_type(8))) short short8;
typedef __attribute__((ext_vector_type(4))) float f32x4;
typedef __attribute__((ext_vector_type(4))) int i32x4;

#define QP   960    // padded flat spatial per image (30*30=900, zero-fill to 960)
#define QO   896    // output q range per image (7 tiles * 128)
#define KTOT 2304   // 9 taps * 256 channels
#define NIMG 64
#define CCH  256
#define HW   28
#define PLN  784    // 28*28

__device__ __forceinline__ void gload_lds16(const void* g, void* l) {
  __builtin_amdgcn_global_load_lds((const __attribute__((address_space(1))) void*)g,
                                   (__attribute__((address_space(3))) void*)l, 16, 0, 0);
}

// ------- init: zero Xp borders/tails (i8) + zero rs1/rs2 --------------------
__global__ __launch_bounds__(256) void kinit(int8_t* __restrict__ xp1,
                                             int8_t* __restrict__ xp2,
                                             i32x4* __restrict__ rsz) {
  const int b = blockIdx.x;
  const int t = threadIdx.x;
  const i32x4 z = {0, 0, 0, 0};
  if (b < 128) {
    const int n = b >> 1;
    int8_t* xp = (b & 1) ? xp2 : xp1;
#pragma unroll
    for (int p = 0; p < 11; ++p) {     // 176 rows * 16 chunks = 2816 tasks
      const int task = p * 256 + t;
      const int r = task >> 4, l16 = task & 15;
      int q;
      if (r < 30) q = r;
      else if (r < 60) q = 870 + (r - 30);
      else if (r < 120) q = 900 + (r - 60);
      else { const int k = r - 120; q = (1 + (k >> 1)) * 30 + ((k & 1) ? 29 : 0); }
      ((i32x4*)(xp + ((size_t)n * QP + q) * CCH))[l16] = z;
    }
  } else {
    rsz[(b - 128) * 256 + t] = z;      // 120 blocks cover 30720 chunks
  }
}

// ---------------- weight prep: signs (i8 ±1/0) + per-filter alpha/mean ------
__global__ __launch_bounds__(256) void kwprep(const float* __restrict__ w1,
                                              const float* __restrict__ w2,
                                              int8_t* __restrict__ aw1,
                                              int8_t* __restrict__ aw2,
                                              float* __restrict__ am1,
                                              float* __restrict__ am2) {
  const int o = blockIdx.x & 255;
  const float* w = (blockIdx.x >> 8) ? w2 : w1;
  int8_t* aw = (blockIdx.x >> 8) ? aw2 : aw1;
  float* am = (blockIdx.x >> 8) ? am2 : am1;
  const int t = threadIdx.x;
  const int lane = t & 63, wid = t >> 6;
  const float* wo = w + (size_t)o * KTOT;
  float v[9];
  double s = 0.0;
#pragma unroll
  for (int j = 0; j < 9; ++j) { v[j] = wo[t * 9 + j]; s += (double)v[j]; }
  __shared__ double red[4];
#pragma unroll
  for (int m = 32; m >= 1; m >>= 1) s += __shfl_xor(s, m);
  if (lane == 0) red[wid] = s;
  __syncthreads();
  const double mean = (red[0] + red[1] + red[2] + red[3]) * (1.0 / 2304.0);
  __syncthreads();
  double sq = 0.0;
#pragma unroll
  for (int j = 0; j < 9; ++j) { const double d = (double)v[j] - mean; sq += d * d; }
#pragma unroll
  for (int m = 32; m >= 1; m >>= 1) sq += __shfl_xor(sq, m);
  if (lane == 0) red[wid] = sq;
  __syncthreads();
  const double alpha = sqrt((red[0] + red[1] + red[2] + red[3]) * (1.0 / 2304.0));
#pragma unroll
  for (int j = 0; j < 9; ++j) {
    const double d = (double)v[j] - mean;
    const int sg = d > 0.0 ? 1 : (d < 0.0 ? -1 : 0);
    aw[(size_t)o * KTOT + j * CCH + t] = (int8_t)sg;
  }
  if (t == 0) { am[o] = (float)alpha; am[CCH + o] = (float)mean; }
}

// -------- activation signs (i8) + fused row sums + transposed f32 residual --
__global__ __launch_bounds__(256) void kaprep(const float* __restrict__ x,
                                              const float* __restrict__ alpha,
                                              const float* __restrict__ beta,
                                              int8_t* __restrict__ xp,
                                              float* __restrict__ rs,
                                              float* __restrict__ xT) {
  const int n = blockIdx.x / HW;
  const int h = blockIdx.x % HW;
  const int c = threadIdx.x;
  const float a = alpha[c], bt = beta[c];
  const float* src = x + ((size_t)(n * CCH + c)) * PLN + h * HW;
  __shared__ int8_t tile[CCH][HW];
#pragma unroll
  for (int j = 0; j < 7; ++j) {
    float4 f = ((const float4*)src)[j];
    float vv[4] = {f.x, f.y, f.z, f.w};
#pragma unroll
    for (int e = 0; e < 4; ++e) {
      const float xa = (vv[e] - bt) / a;
      const float sg = xa > 0.f ? 1.f : (xa < 0.f ? -1.f : 0.f);
      tile[c][j * 4 + e] = (int8_t)__float2int_rn(sg * a + bt);
      xT[((size_t)n * PLN + h * HW + j * 4 + e) * CCH + c] = vv[e];  // coalesced
    }
  }
  __syncthreads();
  int8_t* dst = xp + ((size_t)n * QP + (h + 1) * 30 + 1) * CCH;
#pragma unroll
  for (int ww = 0; ww < HW; ++ww) dst[ww * CCH + c] = tile[c][ww];
  const int ww = c >> 3, sub = c & 7;
  if (ww < HW) {
    int s = 0;
#pragma unroll
    for (int cc = 0; cc < 32; ++cc) s += (int)tile[sub * 32 + cc][ww];
    s += __shfl_xor(s, 4); s += __shfl_xor(s, 2); s += __shfl_xor(s, 1);
    if (sub == 0) rs[(size_t)n * QP + (h + 1) * 30 + 1 + ww] = (float)s;
  }
}

// ---------------- T[n*QO+q] = 9-tap sum of rs ------------------------------
__global__ __launch_bounds__(256) void kT(const float* __restrict__ rs,
                                          float* __restrict__ T) {
  const int idx = blockIdx.x * 256 + threadIdx.x;
  const int n = idx / QO, q = idx % QO;
  const float* r = rs + (size_t)n * QP + q;
  float s = 0.f;
#pragma unroll
  for (int kh = 0; kh < 3; ++kh)
#pragma unroll
    for (int kw = 0; kw < 3; ++kw) s += r[kh * 30 + kw];
  T[idx] = s;
}

// ---------------- implicit-GEMM conv (exact i8/i32 S) + fused epilogue ------
// BK=64 i8; packed LDS: two 64B tile-rows per 128B LDS row, chunk-XOR swizzle
// pc = ((p&1)*4+g) ^ ((p>>1)&7)  -> 2-way (free) bank pattern on ds_read_b128.
// Double-buffered (2 x 16KB), 36 K-steps, 34.8KB LDS -> 4 blocks/CU resident.
// EPI1: D[q][o]; writes Xp2 (i8), x1T[n][o][q] bf16 via LDS transpose,
//       rs2 atomics; residual from xT[n][p][c] f32.
// EPI2: D[o][q] (swapped operands); writes out NCHW coalesced along w.
template <int EPI>
__global__ __launch_bounds__(256, 4) void kconv(
    const int8_t* __restrict__ xp, const int8_t* __restrict__ aw,
    const float* __restrict__ am,       // [0..255]=alpha_w, [256..511]=mean_w
    const float* __restrict__ T,        // [n][QO]
    const float* __restrict__ bng, const float* __restrict__ bnb,
    const float* __restrict__ bnm, const float* __restrict__ bnv,
    const float* __restrict__ pos, const float* __restrict__ neg,
    const float* __restrict__ xT,       // EPI==1: residual, [n][PLN][c] f32
    const bf16* __restrict__ x1r,       // EPI==2: x1T [n][CCH][QO] bf16
    const float* __restrict__ a2, const float* __restrict__ b2,  // EPI==1
    int8_t* __restrict__ xpn,           // EPI==1: Xp2 interior (i8)
    bf16* __restrict__ x1t,             // EPI==1: x1T [n][CCH][QO] bf16
    float* __restrict__ rsn,            // EPI==1: rs2 accumulation (atomics)
    float* __restrict__ out)            // EPI==2: NCHW f32
{
  __shared__ char lds[34816];           // 2 bufs * (A 8KB + B 8KB) + tb reuse
  const int bid0 = blockIdx.x;
  const int bid = (bid0 & 7) * 112 + (bid0 >> 3);   // bijective XCD swizzle
  const int nt = bid & 1;
  const int mt = bid >> 1;
  const int n = mt / 7;
  const int qt = (mt % 7) * 128;
  const int o0 = nt * 128;
  const int t = threadIdx.x;
  const int lane = t & 63, wid = t >> 6;
  const int wp = (wid >> 1) * 64, wo = (wid & 1) * 64;

  // staging decomposition: thread t writes physical chunk (rowp, pcS) of each
  // 64-LDS-row half; logical chunk cS -> tile-row parity pS, k-granule k16S.
  const int rowp = t >> 3;              // LDS row' 0..31 (+32 for it=1)
  const int pcS = t & 7;                // physical 16B chunk written
  const int cS = pcS ^ (rowp & 7);      // logical chunk (inverse swizzle)
  const int pS = cS >> 2;               // tile-row parity
  const int k16S = cS & 3;              // k granule

  i32x4 acc[4][4];
#pragma unroll
  for (int i = 0; i < 4; ++i)
#pragma unroll
    for (int j = 0; j < 4; ++j) acc[i][j] = (i32x4){0, 0, 0, 0};

  const int r16 = lane & 15;
  const int g = lane >> 4;              // k-granule 0..3 (16 i8 each)
  const int g4 = g * 4;
  const int rsh = r16 >> 1;
  const int pc0 = ((r16 & 1) * 4 + g) ^ rsh;   // physical chunk for frag read
  const int wpH = (wid >> 1) * 32, woH = (wid & 1) * 32;

  const int8_t* baseA = xp + ((size_t)(n * QP + qt + 2 * rowp + pS)) * CCH + k16S * 16;
  const int8_t* baseB = aw + ((size_t)(o0 + 2 * rowp + pS)) * KTOT + k16S * 16;

  auto STAGE = [&](int buf, int ks) {
    const int tap = ks >> 2, i0 = (ks & 3) * 64;
    const int sh = (tap / 3) * 30 + (tap % 3);     // constant under unroll
    const int8_t* sA = baseA + (size_t)sh * CCH + i0;
    const int8_t* sB = baseB + (size_t)ks * 64;
    char* dA = lds + buf * 16384;
    char* dB = dA + 8192;
    const int d0 = rowp * 128 + pcS * 16;
    gload_lds16(sA, dA + d0);
    gload_lds16(sB, dB + d0);
    gload_lds16(sA + 64 * CCH, dA + 4096 + d0);
    gload_lds16(sB + (size_t)64 * KTOT, dB + 4096 + d0);
  };

  STAGE(0, 0);
  __syncthreads();

#pragma unroll
  for (int ks = 0; ks < 36; ++ks) {
    const int cur = ks & 1;
    if (ks < 35) STAGE(cur ^ 1, ks + 1);
    const char* pA = lds + cur * 16384;
    const char* pB = pA + 8192;
    const char* p1 = (EPI == 1) ? pA : pB;
    const char* p2 = (EPI == 1) ? pB : pA;
    i32x4 f1[4], f2[4];
#pragma unroll
    for (int m = 0; m < 4; ++m) {
      f1[m] = *(const i32x4*)&p1[(wpH + m * 8 + rsh) * 128 + pc0 * 16];
      f2[m] = *(const i32x4*)&p2[(woH + m * 8 + rsh) * 128 + pc0 * 16];
    }
    __builtin_amdgcn_s_setprio(1);
#pragma unroll
    for (int m = 0; m < 4; ++m)
#pragma unroll
      for (int nn = 0; nn < 4; ++nn)
        acc[m][nn] = __builtin_amdgcn_mfma_i32_16x16x64_i8(
            f1[m], f2[nn], acc[m][nn], 0, 0, 0);
    __builtin_amdgcn_s_setprio(0);
    __syncthreads();
  }

  if constexpr (EPI == 1) {
    // D[q = qt+wp+m*16+g4+r][o = o0+wo+nn*16+r16]
    int oc[4];
    float invc[4], addc[4], ppc[4], ngc[4], awc[4], mwc[4], aac[4], bbc[4];
#pragma unroll
    for (int nn = 0; nn < 4; ++nn) {
      const int o = o0 + wo + nn * 16 + r16;
      oc[nn] = o;
      const float inv = bng[o] / sqrtf(bnv[o] + 1e-5f);
      invc[nn] = inv;
      addc[nn] = bnb[o] - bnm[o] * inv;
      ppc[nn] = pos[o]; ngc[nn] = neg[o];
      awc[nn] = am[o];  mwc[nn] = am[CCH + o];
      aac[nn] = a2[o];  bbc[nn] = b2[o];
    }
    short* tb = (short*)lds;            // [128][136] transpose staging
#pragma unroll
    for (int m = 0; m < 4; ++m) {
#pragma unroll
      for (int r = 0; r < 4; ++r) {
        const int ql = wp + m * 16 + g4 + r;
        const int q = qt + ql;
        const int hh = q / 30, ww2 = q % 30;
        if (hh < HW && ww2 < HW) {      // uniform per 16-lane group
          const float tq = T[(size_t)n * QO + q];
          const float* xrow = xT + ((size_t)n * PLN + hh * HW + ww2) * CCH;
          float rowsum = 0.f;
#pragma unroll
          for (int nn = 0; nn < 4; ++nn) {
            const int o = oc[nn];
            float v = awc[nn] * (float)acc[m][nn][r] + mwc[nn] * tq;
            v = v * invc[nn] + addc[nn];
            v += xrow[o];               // coalesced 64B per 16-group
            v = v > 0.f ? ppc[nn] * v : ngc[nn] * v;
            const float xa = (v - bbc[nn]) / aac[nn];
            const float sg = xa > 0.f ? 1.f : (xa < 0.f ? -1.f : 0.f);
            const float bv = sg * aac[nn] + bbc[nn];
            rowsum += bv;
            xpn[((size_t)n * QP + (hh + 1) * 30 + (ww2 + 1)) * CCH + o] =
                (int8_t)__float2int_rn(bv);
            bf16 hb = __float2bfloat16(v);
            tb[(wo + nn * 16 + r16) * 136 + ql] = *reinterpret_cast<short*>(&hb);
          }
          rowsum += __shfl_xor(rowsum, 8); rowsum += __shfl_xor(rowsum, 4);
          rowsum += __shfl_xor(rowsum, 2); rowsum += __shfl_xor(rowsum, 1);
          if (r16 == 0)
            atomicAdd(&rsn[(size_t)n * QP + (hh + 1) * 30 + (ww2 + 1)], rowsum);
        }
      }
    }
    __syncthreads();
    // transpose readout: x1T[n][o0+o_l][qt + half*64 ..] coalesced 16B
    {
      const int o_l = t >> 1, half = t & 1;
      short* x1s = (short*)x1t;
      const size_t gbase = ((size_t)(n * CCH + o0 + o_l)) * QO + qt + half * 64;
#pragma unroll
      for (int j = 0; j < 8; ++j)
        *(short8*)(x1s + gbase + j * 8) = *(const short8*)&tb[o_l * 136 + half * 64 + j * 8];
    }
  } else {
    // D[o = o0+wp+m*16+g4+r][q = qt+wo+nn*16+c16]
    float* cst = (float*)lds;           // [5][128] per-o fused constants
    if (t < 128) {
      const int o = o0 + t;
      const float inv = bng[o] / sqrtf(bnv[o] + 1e-5f);
      cst[t]       = am[o] * inv;           // alpha_w * inv
      cst[128 + t] = am[CCH + o] * inv;     // mean_w * inv
      cst[256 + t] = bnb[o] - bnm[o] * inv; // additive
      cst[384 + t] = pos[o];
      cst[512 + t] = neg[o];
    }
    __syncthreads();
    const int c16 = lane & 15;
#pragma unroll
    for (int nn = 0; nn < 4; ++nn) {
      const int q = qt + wo + nn * 16 + c16;
      const int hh = q / 30, ww2 = q % 30;
      const bool valid = (hh < HW) && (ww2 < HW);
      const float tq = T[(size_t)n * QO + q];
#pragma unroll
      for (int m = 0; m < 4; ++m) {
#pragma unroll
        for (int r = 0; r < 4; ++r) {
          const int ol = wp + m * 16 + g4 + r;
          const int o = o0 + ol;
          if (valid) {
            float v = cst[ol] * (float)acc[m][nn][r] + cst[128 + ol] * tq + cst[256 + ol];
            v += __bfloat162float(x1r[((size_t)(n * CCH + o)) * QO + q]);
            v = v > 0.f ? cst[384 + ol] * v : cst[512 + ol] * v;
            out[((size_t)(n * CCH + o)) * PLN + hh * HW + ww2] = v;
          }
        }
      }
    }
  }
}

extern "C" void kernel_launch(void* const* d_in, const int* in_sizes, int n_in,
                              void* d_out, int out_size, void* d_ws, size_t ws_size,
                              hipStream_t stream) {
  const float* x   = (const float*)d_in[0];
  const float* w1  = (const float*)d_in[1];
  const float* al1 = (const float*)d_in[2];
  const float* be1 = (const float*)d_in[3];
  const float* g1  = (const float*)d_in[4];
  const float* bb1 = (const float*)d_in[5];
  const float* m1  = (const float*)d_in[6];
  const float* v1  = (const float*)d_in[7];
  const float* p1  = (const float*)d_in[8];
  const float* n1  = (const float*)d_in[9];
  const float* w2  = (const float*)d_in[10];
  const float* al2 = (const float*)d_in[11];
  const float* be2 = (const float*)d_in[12];
  const float* g2  = (const float*)d_in[13];
  const float* bb2 = (const float*)d_in[14];
  const float* m2  = (const float*)d_in[15];
  const float* v2  = (const float*)d_in[16];
  const float* p2  = (const float*)d_in[17];
  const float* n2  = (const float*)d_in[18];
  float* out = (float*)d_out;

  char* ws = (char*)d_ws;
  // workspace layout (bytes):
  //   Xp1 @ 0          : 15,728,640   [64][960][256] i8
  //   Xp2 @ 15,728,640 : 15,728,640
  //   x1T @ 31,457,280 : 29,360,128   [64][256][896] bf16
  //   Aw1 @ 60,817,408 :    589,824   [256][2304] i8
  //   Aw2 @ 61,407,232 :    589,824
  //   am1 @ 61,997,056 :      2,048
  //   am2 @ 61,999,104 :      2,048
  //   rs1 @ 62,001,152 :    245,760   [64][960] f32
  //   rs2 @ 62,246,912 :    245,760
  //   Tb  @ 62,492,672 :    229,376   [64][896] f32   (total 62,722,048)
  // xT (transposed f32 residual, [64][784][256]) lives in d_out (same size).
  int8_t* Xp1 = (int8_t*)(ws);
  int8_t* Xp2 = (int8_t*)(ws + 15728640);
  bf16*   X1T = (bf16*)(ws + 31457280);
  int8_t* Aw1 = (int8_t*)(ws + 60817408);
  int8_t* Aw2 = (int8_t*)(ws + 61407232);
  float*  am1 = (float*)(ws + 61997056);
  float*  am2 = (float*)(ws + 61999104);
  float*  rs1 = (float*)(ws + 62001152);
  float*  rs2 = (float*)(ws + 62246912);
  float*  Tb  = (float*)(ws + 62492672);
  float*  xT  = out;  // reused as scratch; kconv2 overwrites with final output

  kinit<<<248, 256, 0, stream>>>(Xp1, Xp2, (i32x4*)rs1);   // rs1+rs2 contiguous
  kwprep<<<512, 256, 0, stream>>>(w1, w2, Aw1, Aw2, am1, am2);
  kaprep<<<NIMG * HW, 256, 0, stream>>>(x, al1, be1, Xp1, rs1, xT);
  kT<<<NIMG * QO / 256, 256, 0, stream>>>(rs1, Tb);
  kconv<1><<<896, 256, 0, stream>>>(Xp1, Aw1, am1, Tb, g1, bb1, m1, v1, p1, n1,
                                    xT, nullptr, al2, be2, Xp2, X1T, rs2, nullptr);
  kT<<<NIMG * QO / 256, 256, 0, stream>>>(rs2, Tb);
  kconv<2><<<896, 256, 0, stream>>>(Xp2, Aw2, am2, Tb, g2, bb2, m2, v2, p2, n2,
                                    nullptr, X1T, nullptr, nullptr, nullptr, nullptr,
                                    nullptr, out);
}

// Round 7
// 171.491 us; speedup vs baseline: 1.0766x; 1.0766x over previous
//
#include <hip/hip_runtime.h>
#include <hip/hip_bf16.h>

using bf16 = __hip_bfloat16;
typedef __attribute__((ext_vector_type(8))) short short8;
typedef __attribute__((ext_vector_type(4))) float f32x4;
typedef __attribute__((ext_vector_type(4))) int i32x4;

#define QP   960    // padded flat spatial per image (30*30=900, zero-fill to 960)
#define QO   896    // output q range per image (7 tiles * 128)
#define KTOT 2304   // 9 taps * 256 channels
#define NIMG 64
#define CCH  256
#define HW   28
#define PLN  784    // 28*28

__device__ __forceinline__ void gload_lds16(const void* g, void* l) {
  __builtin_amdgcn_global_load_lds((const __attribute__((address_space(1))) void*)g,
                                   (__attribute__((address_space(3))) void*)l, 16, 0, 0);
}

// ------- init: zero Xp borders/tails (i8) + zero rs1/rs2 --------------------
__global__ __launch_bounds__(256) void kinit(int8_t* __restrict__ xp1,
                                             int8_t* __restrict__ xp2,
                                             i32x4* __restrict__ rsz) {
  const int b = blockIdx.x;
  const int t = threadIdx.x;
  const i32x4 z = {0, 0, 0, 0};
  if (b < 128) {
    const int n = b >> 1;
    int8_t* xp = (b & 1) ? xp2 : xp1;
#pragma unroll
    for (int p = 0; p < 11; ++p) {     // 176 rows * 16 chunks = 2816 tasks
      const int task = p * 256 + t;
      const int r = task >> 4, l16 = task & 15;
      int q;
      if (r < 30) q = r;
      else if (r < 60) q = 870 + (r - 30);
      else if (r < 120) q = 900 + (r - 60);
      else { const int k = r - 120; q = (1 + (k >> 1)) * 30 + ((k & 1) ? 29 : 0); }
      ((i32x4*)(xp + ((size_t)n * QP + q) * CCH))[l16] = z;
    }
  } else {
    rsz[(b - 128) * 256 + t] = z;      // 120 blocks cover 30720 chunks
  }
}

// ---------------- weight prep: signs (i8 ±1/0) + per-filter alpha/mean ------
__global__ __launch_bounds__(256) void kwprep(const float* __restrict__ w1,
                                              const float* __restrict__ w2,
                                              int8_t* __restrict__ aw1,
                                              int8_t* __restrict__ aw2,
                                              float* __restrict__ am1,
                                              float* __restrict__ am2) {
  const int o = blockIdx.x & 255;
  const float* w = (blockIdx.x >> 8) ? w2 : w1;
  int8_t* aw = (blockIdx.x >> 8) ? aw2 : aw1;
  float* am = (blockIdx.x >> 8) ? am2 : am1;
  const int t = threadIdx.x;
  const int lane = t & 63, wid = t >> 6;
  const float* wo = w + (size_t)o * KTOT;
  float v[9];
  double s = 0.0;
#pragma unroll
  for (int j = 0; j < 9; ++j) { v[j] = wo[t * 9 + j]; s += (double)v[j]; }
  __shared__ double red[4];
#pragma unroll
  for (int m = 32; m >= 1; m >>= 1) s += __shfl_xor(s, m);
  if (lane == 0) red[wid] = s;
  __syncthreads();
  const double mean = (red[0] + red[1] + red[2] + red[3]) * (1.0 / 2304.0);
  __syncthreads();
  double sq = 0.0;
#pragma unroll
  for (int j = 0; j < 9; ++j) { const double d = (double)v[j] - mean; sq += d * d; }
#pragma unroll
  for (int m = 32; m >= 1; m >>= 1) sq += __shfl_xor(sq, m);
  if (lane == 0) red[wid] = sq;
  __syncthreads();
  const double alpha = sqrt((red[0] + red[1] + red[2] + red[3]) * (1.0 / 2304.0));
#pragma unroll
  for (int j = 0; j < 9; ++j) {
    const double d = (double)v[j] - mean;
    const int sg = d > 0.0 ? 1 : (d < 0.0 ? -1 : 0);
    aw[(size_t)o * KTOT + j * CCH + t] = (int8_t)sg;
  }
  if (t == 0) { am[o] = (float)alpha; am[CCH + o] = (float)mean; }
}

// -------- activation signs (i8) + fused row sums + transposed f32 residual --
__global__ __launch_bounds__(256) void kaprep(const float* __restrict__ x,
                                              const float* __restrict__ alpha,
                                              const float* __restrict__ beta,
                                              int8_t* __restrict__ xp,
                                              float* __restrict__ rs,
                                              float* __restrict__ xT) {
  const int n = blockIdx.x / HW;
  const int h = blockIdx.x % HW;
  const int c = threadIdx.x;
  const float a = alpha[c], bt = beta[c];
  const float* src = x + ((size_t)(n * CCH + c)) * PLN + h * HW;
  __shared__ int8_t tile[CCH][HW];
#pragma unroll
  for (int j = 0; j < 7; ++j) {
    float4 f = ((const float4*)src)[j];
    float vv[4] = {f.x, f.y, f.z, f.w};
#pragma unroll
    for (int e = 0; e < 4; ++e) {
      const float xa = (vv[e] - bt) / a;
      const float sg = xa > 0.f ? 1.f : (xa < 0.f ? -1.f : 0.f);
      tile[c][j * 4 + e] = (int8_t)__float2int_rn(sg * a + bt);
      xT[((size_t)n * PLN + h * HW + j * 4 + e) * CCH + c] = vv[e];  // coalesced
    }
  }
  __syncthreads();
  int8_t* dst = xp + ((size_t)n * QP + (h + 1) * 30 + 1) * CCH;
#pragma unroll
  for (int ww = 0; ww < HW; ++ww) dst[ww * CCH + c] = tile[c][ww];
  const int ww = c >> 3, sub = c & 7;
  if (ww < HW) {
    int s = 0;
#pragma unroll
    for (int cc = 0; cc < 32; ++cc) s += (int)tile[sub * 32 + cc][ww];
    s += __shfl_xor(s, 4); s += __shfl_xor(s, 2); s += __shfl_xor(s, 1);
    if (sub == 0) rs[(size_t)n * QP + (h + 1) * 30 + 1 + ww] = (float)s;
  }
}

// ---------------- implicit-GEMM conv (exact i8/i32 S) + fused epilogue ------
// BK=64 i8, packed-chunk XOR-swizzled LDS, TRIPLE-buffered ring with depth-2
// prefetch + counted vmcnt(4) + raw s_barrier (T3/T4: loads stay in flight
// across barriers; drain only at the tail). 48KB LDS -> 3 blocks/CU.
// T computed inline from rs (9-tap) in the epilogues.
template <int EPI>
__global__ __launch_bounds__(256, 3) void kconv(
    const int8_t* __restrict__ xp, const int8_t* __restrict__ aw,
    const float* __restrict__ am,       // [0..255]=alpha_w, [256..511]=mean_w
    const float* __restrict__ rs,       // [n][QP] row sums (for inline T)
    const float* __restrict__ bng, const float* __restrict__ bnb,
    const float* __restrict__ bnm, const float* __restrict__ bnv,
    const float* __restrict__ pos, const float* __restrict__ neg,
    const float* __restrict__ xT,       // EPI==1: residual, [n][PLN][c] f32
    const bf16* __restrict__ x1r,       // EPI==2: x1T [n][CCH][QO] bf16
    const float* __restrict__ a2, const float* __restrict__ b2,  // EPI==1
    int8_t* __restrict__ xpn,           // EPI==1: Xp2 interior (i8)
    bf16* __restrict__ x1t,             // EPI==1: x1T [n][CCH][QO] bf16
    float* __restrict__ rsn,            // EPI==1: rs2 accumulation (atomics)
    float* __restrict__ out)            // EPI==2: NCHW f32
{
  __shared__ char lds[49152];           // 3 bufs * (A 8KB + B 8KB); epi reuses
  const int bid0 = blockIdx.x;
  const int bid = (bid0 & 7) * 112 + (bid0 >> 3);   // bijective XCD swizzle
  const int nt = bid & 1;
  const int mt = bid >> 1;
  const int n = mt / 7;
  const int qt = (mt % 7) * 128;
  const int o0 = nt * 128;
  const int t = threadIdx.x;
  const int lane = t & 63, wid = t >> 6;
  const int wp = (wid >> 1) * 64, wo = (wid & 1) * 64;

  // staging decomposition (unchanged from r6): thread t writes physical chunk
  // (rowp, pcS); logical chunk cS = pcS ^ (rowp&7) -> parity pS, granule k16S.
  const int rowp = t >> 3;
  const int pcS = t & 7;
  const int cS = pcS ^ (rowp & 7);
  const int pS = cS >> 2;
  const int k16S = cS & 3;

  i32x4 acc[4][4];
#pragma unroll
  for (int i = 0; i < 4; ++i)
#pragma unroll
    for (int j = 0; j < 4; ++j) acc[i][j] = (i32x4){0, 0, 0, 0};

  const int r16 = lane & 15;
  const int g = lane >> 4;
  const int g4 = g * 4;
  const int rsh = r16 >> 1;
  const int pc0 = ((r16 & 1) * 4 + g) ^ rsh;   // physical chunk for frag read
  const int wpH = (wid >> 1) * 32, woH = (wid & 1) * 32;

  const int8_t* baseA = xp + ((size_t)(n * QP + qt + 2 * rowp + pS)) * CCH + k16S * 16;
  const int8_t* baseB = aw + ((size_t)(o0 + 2 * rowp + pS)) * KTOT + k16S * 16;

  auto STAGE = [&](int buf, int ks) {
    const int tap = ks >> 2, i0 = (ks & 3) * 64;
    const int sh = (tap / 3) * 30 + (tap % 3);     // constant under unroll
    const int8_t* sA = baseA + (size_t)sh * CCH + i0;
    const int8_t* sB = baseB + (size_t)ks * 64;
    char* dA = lds + buf * 16384;
    char* dB = dA + 8192;
    const int d0 = rowp * 128 + pcS * 16;
    gload_lds16(sA, dA + d0);
    gload_lds16(sB, dB + d0);
    gload_lds16(sA + 64 * CCH, dA + 4096 + d0);
    gload_lds16(sB + (size_t)64 * KTOT, dB + 4096 + d0);
  };

  STAGE(0, 0);
  STAGE(1, 1);
  asm volatile("s_waitcnt vmcnt(4)" ::: "memory");   // STAGE(0) complete
  __builtin_amdgcn_s_barrier();

#pragma unroll
  for (int ks = 0; ks < 36; ++ks) {
    const int cur = ks % 3;
    const char* pA = lds + cur * 16384;
    const char* pB = pA + 8192;
    const char* p1 = (EPI == 1) ? pA : pB;
    const char* p2 = (EPI == 1) ? pB : pA;
    i32x4 f1[4], f2[4];
#pragma unroll
    for (int m = 0; m < 4; ++m) {
      f1[m] = *(const i32x4*)&p1[(wpH + m * 8 + rsh) * 128 + pc0 * 16];
      f2[m] = *(const i32x4*)&p2[(woH + m * 8 + rsh) * 128 + pc0 * 16];
    }
    if (ks < 34) STAGE((ks + 2) % 3, ks + 2);
    __builtin_amdgcn_s_setprio(1);
#pragma unroll
    for (int m = 0; m < 4; ++m)
#pragma unroll
      for (int nn = 0; nn < 4; ++nn)
        acc[m][nn] = __builtin_amdgcn_mfma_i32_16x16x64_i8(
            f1[m], f2[nn], acc[m][nn], 0, 0, 0);
    __builtin_amdgcn_s_setprio(0);
    if (ks < 34) {
      // outstanding: STAGE(ks+1) 4 + STAGE(ks+2) 4 -> wait STAGE(ks+1) done,
      // keep STAGE(ks+2)'s 4 loads in flight across the barrier.
      asm volatile("s_waitcnt vmcnt(4)" ::: "memory");
    } else {
      asm volatile("s_waitcnt vmcnt(0)" ::: "memory");
    }
    __builtin_amdgcn_s_barrier();
  }

  if constexpr (EPI == 1) {
    // D[q = qt+wp+m*16+g4+r][o = o0+wo+nn*16+r16]
    int oc[4];
    float invc[4], addc[4], ppc[4], ngc[4], awc[4], mwc[4], aac[4], bbc[4];
#pragma unroll
    for (int nn = 0; nn < 4; ++nn) {
      const int o = o0 + wo + nn * 16 + r16;
      oc[nn] = o;
      const float inv = bng[o] / sqrtf(bnv[o] + 1e-5f);
      invc[nn] = inv;
      addc[nn] = bnb[o] - bnm[o] * inv;
      ppc[nn] = pos[o]; ngc[nn] = neg[o];
      awc[nn] = am[o];  mwc[nn] = am[CCH + o];
      aac[nn] = a2[o];  bbc[nn] = b2[o];
    }
    short* tb = (short*)lds;            // [128][136] transpose staging
#pragma unroll
    for (int m = 0; m < 4; ++m) {
#pragma unroll
      for (int r = 0; r < 4; ++r) {
        const int ql = wp + m * 16 + g4 + r;
        const int q = qt + ql;
        const int hh = q / 30, ww2 = q % 30;
        if (hh < HW && ww2 < HW) {      // uniform per 16-lane group
          const float* rrow = rs + (size_t)n * QP + q;
          float tq = 0.f;
#pragma unroll
          for (int kh = 0; kh < 3; ++kh)
#pragma unroll
            for (int kw = 0; kw < 3; ++kw) tq += rrow[kh * 30 + kw];
          const float* xrow = xT + ((size_t)n * PLN + hh * HW + ww2) * CCH;
          float rowsum = 0.f;
#pragma unroll
          for (int nn = 0; nn < 4; ++nn) {
            const int o = oc[nn];
            float v = awc[nn] * (float)acc[m][nn][r] + mwc[nn] * tq;
            v = v * invc[nn] + addc[nn];
            v += xrow[o];               // coalesced 64B per 16-group
            v = v > 0.f ? ppc[nn] * v : ngc[nn] * v;
            const float xa = (v - bbc[nn]) / aac[nn];
            const float sg = xa > 0.f ? 1.f : (xa < 0.f ? -1.f : 0.f);
            const float bv = sg * aac[nn] + bbc[nn];
            rowsum += bv;
            xpn[((size_t)n * QP + (hh + 1) * 30 + (ww2 + 1)) * CCH + o] =
                (int8_t)__float2int_rn(bv);
            bf16 hb = __float2bfloat16(v);
            tb[(wo + nn * 16 + r16) * 136 + ql] = *reinterpret_cast<short*>(&hb);
          }
          rowsum += __shfl_xor(rowsum, 8); rowsum += __shfl_xor(rowsum, 4);
          rowsum += __shfl_xor(rowsum, 2); rowsum += __shfl_xor(rowsum, 1);
          if (r16 == 0)
            atomicAdd(&rsn[(size_t)n * QP + (hh + 1) * 30 + (ww2 + 1)], rowsum);
        }
      }
    }
    __syncthreads();
    // transpose readout: x1T[n][o0+o_l][qt + half*64 ..] coalesced 16B
    {
      const int o_l = t >> 1, half = t & 1;
      short* x1s = (short*)x1t;
      const size_t gbase = ((size_t)(n * CCH + o0 + o_l)) * QO + qt + half * 64;
#pragma unroll
      for (int j = 0; j < 8; ++j)
        *(short8*)(x1s + gbase + j * 8) = *(const short8*)&tb[o_l * 136 + half * 64 + j * 8];
    }
  } else {
    // D[o = o0+wp+m*16+g4+r][q = qt+wo+nn*16+c16]
    float* cst = (float*)lds;           // [5][128] per-o fused constants
    if (t < 128) {
      const int o = o0 + t;
      const float inv = bng[o] / sqrtf(bnv[o] + 1e-5f);
      cst[t]       = am[o] * inv;           // alpha_w * inv
      cst[128 + t] = am[CCH + o] * inv;     // mean_w * inv
      cst[256 + t] = bnb[o] - bnm[o] * inv; // additive
      cst[384 + t] = pos[o];
      cst[512 + t] = neg[o];
    }
    __syncthreads();
    const int c16 = lane & 15;
#pragma unroll
    for (int nn = 0; nn < 4; ++nn) {
      const int q = qt + wo + nn * 16 + c16;
      const int hh = q / 30, ww2 = q % 30;
      const bool valid = (hh < HW) && (ww2 < HW);
      const float* rrow = rs + (size_t)n * QP + q;
      float tq = 0.f;
#pragma unroll
      for (int kh = 0; kh < 3; ++kh)
#pragma unroll
        for (int kw = 0; kw < 3; ++kw) tq += rrow[kh * 30 + kw];
#pragma unroll
      for (int m = 0; m < 4; ++m) {
#pragma unroll
        for (int r = 0; r < 4; ++r) {
          const int ol = wp + m * 16 + g4 + r;
          const int o = o0 + ol;
          if (valid) {
            float v = cst[ol] * (float)acc[m][nn][r] + cst[128 + ol] * tq + cst[256 + ol];
            v += __bfloat162float(x1r[((size_t)(n * CCH + o)) * QO + q]);
            v = v > 0.f ? cst[384 + ol] * v : cst[512 + ol] * v;
            out[((size_t)(n * CCH + o)) * PLN + hh * HW + ww2] = v;
          }
        }
      }
    }
  }
}

extern "C" void kernel_launch(void* const* d_in, const int* in_sizes, int n_in,
                              void* d_out, int out_size, void* d_ws, size_t ws_size,
                              hipStream_t stream) {
  const float* x   = (const float*)d_in[0];
  const float* w1  = (const float*)d_in[1];
  const float* al1 = (const float*)d_in[2];
  const float* be1 = (const float*)d_in[3];
  const float* g1  = (const float*)d_in[4];
  const float* bb1 = (const float*)d_in[5];
  const float* m1  = (const float*)d_in[6];
  const float* v1  = (const float*)d_in[7];
  const float* p1  = (const float*)d_in[8];
  const float* n1  = (const float*)d_in[9];
  const float* w2  = (const float*)d_in[10];
  const float* al2 = (const float*)d_in[11];
  const float* be2 = (const float*)d_in[12];
  const float* g2  = (const float*)d_in[13];
  const float* bb2 = (const float*)d_in[14];
  const float* m2  = (const float*)d_in[15];
  const float* v2  = (const float*)d_in[16];
  const float* p2  = (const float*)d_in[17];
  const float* n2  = (const float*)d_in[18];
  float* out = (float*)d_out;

  char* ws = (char*)d_ws;
  // workspace layout (bytes):
  //   Xp1 @ 0          : 15,728,640   [64][960][256] i8
  //   Xp2 @ 15,728,640 : 15,728,640
  //   x1T @ 31,457,280 : 29,360,128   [64][256][896] bf16
  //   Aw1 @ 60,817,408 :    589,824   [256][2304] i8
  //   Aw2 @ 61,407,232 :    589,824
  //   am1 @ 61,997,056 :      2,048
  //   am2 @ 61,999,104 :      2,048
  //   rs1 @ 62,001,152 :    245,760   [64][960] f32
  //   rs2 @ 62,246,912 :    245,760   (total 62,492,672)
  // xT (transposed f32 residual, [64][784][256]) lives in d_out (same size).
  int8_t* Xp1 = (int8_t*)(ws);
  int8_t* Xp2 = (int8_t*)(ws + 15728640);
  bf16*   X1T = (bf16*)(ws + 31457280);
  int8_t* Aw1 = (int8_t*)(ws + 60817408);
  int8_t* Aw2 = (int8_t*)(ws + 61407232);
  float*  am1 = (float*)(ws + 61997056);
  float*  am2 = (float*)(ws + 61999104);
  float*  rs1 = (float*)(ws + 62001152);
  float*  rs2 = (float*)(ws + 62246912);
  float*  xT  = out;  // reused as scratch; kconv2 overwrites with final output

  kinit<<<248, 256, 0, stream>>>(Xp1, Xp2, (i32x4*)rs1);   // rs1+rs2 contiguous
  kwprep<<<512, 256, 0, stream>>>(w1, w2, Aw1, Aw2, am1, am2);
  kaprep<<<NIMG * HW, 256, 0, stream>>>(x, al1, be1, Xp1, rs1, xT);
  kconv<1><<<896, 256, 0, stream>>>(Xp1, Aw1, am1, rs1, g1, bb1, m1, v1, p1, n1,
                                    xT, nullptr, al2, be2, Xp2, X1T, rs2, nullptr);
  kconv<2><<<896, 256, 0, stream>>>(Xp2, Aw2, am2, rs2, g2, bb2, m2, v2, p2, n2,
                                    nullptr, X1T, nullptr, nullptr, nullptr, nullptr,
                                    nullptr, out);
}

// Round 9
// 157.923 us; speedup vs baseline: 1.1691x; 1.0859x over previous
//
#include <hip/hip_runtime.h>
#include <hip/hip_bf16.h>

using bf16 = __hip_bfloat16;
typedef __attribute__((ext_vector_type(8))) short short8;
typedef __attribute__((ext_vector_type(4))) float f32x4;
typedef __attribute__((ext_vector_type(4))) int i32x4;

#define QP   960    // padded flat spatial per image (30*30=900, zero-fill to 960)
#define QO   896    // output q range per image (7 tiles * 128)
#define KTOT 2304   // 9 taps * 256 channels
#define NIMG 64
#define CCH  256
#define HW   28
#define PLN  784    // 28*28

__device__ __forceinline__ void gload_lds16(const void* g, void* l) {
  __builtin_amdgcn_global_load_lds((const __attribute__((address_space(1))) void*)g,
                                   (__attribute__((address_space(3))) void*)l, 16, 0, 0);
}

// ------- init: zero Xp borders/tails (i8) + zero rs1/rs2 --------------------
__global__ __launch_bounds__(256) void kinit(int8_t* __restrict__ xp1,
                                             int8_t* __restrict__ xp2,
                                             i32x4* __restrict__ rsz) {
  const int b = blockIdx.x;
  const int t = threadIdx.x;
  const i32x4 z = {0, 0, 0, 0};
  if (b < 128) {
    const int n = b >> 1;
    int8_t* xp = (b & 1) ? xp2 : xp1;
#pragma unroll
    for (int p = 0; p < 11; ++p) {     // 176 rows * 16 chunks = 2816 tasks
      const int task = p * 256 + t;
      const int r = task >> 4, l16 = task & 15;
      int q;
      if (r < 30) q = r;
      else if (r < 60) q = 870 + (r - 30);
      else if (r < 120) q = 900 + (r - 60);
      else { const int k = r - 120; q = (1 + (k >> 1)) * 30 + ((k & 1) ? 29 : 0); }
      ((i32x4*)(xp + ((size_t)n * QP + q) * CCH))[l16] = z;
    }
  } else {
    rsz[(b - 128) * 256 + t] = z;      // 120 blocks cover 30720 chunks
  }
}

// ---------------- weight prep: signs (i8 ±1/0) + per-filter alpha/mean ------
__global__ __launch_bounds__(256) void kwprep(const float* __restrict__ w1,
                                              const float* __restrict__ w2,
                                              int8_t* __restrict__ aw1,
                                              int8_t* __restrict__ aw2,
                                              float* __restrict__ am1,
                                              float* __restrict__ am2) {
  const int o = blockIdx.x & 255;
  const float* w = (blockIdx.x >> 8) ? w2 : w1;
  int8_t* aw = (blockIdx.x >> 8) ? aw2 : aw1;
  float* am = (blockIdx.x >> 8) ? am2 : am1;
  const int t = threadIdx.x;
  const int lane = t & 63, wid = t >> 6;
  const float* wo = w + (size_t)o * KTOT;
  float v[9];
  double s = 0.0;
#pragma unroll
  for (int j = 0; j < 9; ++j) { v[j] = wo[t * 9 + j]; s += (double)v[j]; }
  __shared__ double red[4];
#pragma unroll
  for (int m = 32; m >= 1; m >>= 1) s += __shfl_xor(s, m);
  if (lane == 0) red[wid] = s;
  __syncthreads();
  const double mean = (red[0] + red[1] + red[2] + red[3]) * (1.0 / 2304.0);
  __syncthreads();
  double sq = 0.0;
#pragma unroll
  for (int j = 0; j < 9; ++j) { const double d = (double)v[j] - mean; sq += d * d; }
#pragma unroll
  for (int m = 32; m >= 1; m >>= 1) sq += __shfl_xor(sq, m);
  if (lane == 0) red[wid] = sq;
  __syncthreads();
  const double alpha = sqrt((red[0] + red[1] + red[2] + red[3]) * (1.0 / 2304.0));
#pragma unroll
  for (int j = 0; j < 9; ++j) {
    const double d = (double)v[j] - mean;
    const int sg = d > 0.0 ? 1 : (d < 0.0 ? -1 : 0);
    aw[(size_t)o * KTOT + j * CCH + t] = (int8_t)sg;
  }
  if (t == 0) { am[o] = (float)alpha; am[CCH + o] = (float)mean; }
}

// -------- activation signs (i8) + fused row sums + transposed f32 residual --
__global__ __launch_bounds__(256) void kaprep(const float* __restrict__ x,
                                              const float* __restrict__ alpha,
                                              const float* __restrict__ beta,
                                              int8_t* __restrict__ xp,
                                              float* __restrict__ rs,
                                              float* __restrict__ xT) {
  const int n = blockIdx.x / HW;
  const int h = blockIdx.x % HW;
  const int c = threadIdx.x;
  const float a = alpha[c], bt = beta[c];
  const float* src = x + ((size_t)(n * CCH + c)) * PLN + h * HW;
  __shared__ int8_t tile[CCH][HW];
#pragma unroll
  for (int j = 0; j < 7; ++j) {
    float4 f = ((const float4*)src)[j];
    float vv[4] = {f.x, f.y, f.z, f.w};
#pragma unroll
    for (int e = 0; e < 4; ++e) {
      const float xa = (vv[e] - bt) / a;
      const float sg = xa > 0.f ? 1.f : (xa < 0.f ? -1.f : 0.f);
      tile[c][j * 4 + e] = (int8_t)__float2int_rn(sg * a + bt);
      xT[((size_t)n * PLN + h * HW + j * 4 + e) * CCH + c] = vv[e];  // coalesced
    }
  }
  __syncthreads();
  int8_t* dst = xp + ((size_t)n * QP + (h + 1) * 30 + 1) * CCH;
#pragma unroll
  for (int ww = 0; ww < HW; ++ww) dst[ww * CCH + c] = tile[c][ww];
  const int ww = c >> 3, sub = c & 7;
  if (ww < HW) {
    int s = 0;
#pragma unroll
    for (int cc = 0; cc < 32; ++cc) s += (int)tile[sub * 32 + cc][ww];
    s += __shfl_xor(s, 4); s += __shfl_xor(s, 2); s += __shfl_xor(s, 1);
    if (sub == 0) rs[(size_t)n * QP + (h + 1) * 30 + 1 + ww] = (float)s;
  }
}

// ---------------- implicit-GEMM conv (exact i8/i32 S) + fused epilogue ------
// Persistent-A structure (r8) with the EPI==2 operand-block fix:
//   pixels read at qoff = (EPI==1 ? wp : wo); weights at (EPI==1 ? woH : wpH);
//   mfma(fP,fW) for EPI1, mfma(fW,fP) for EPI2 -> D matches each epilogue.
// A staged once (48KB, row-local chunk-XOR swizzle); loop stages only B
// (8KB/iter, 3-ring, counted vmcnt(2)). 72KB LDS -> 2 blocks/CU.
template <int EPI>
__global__ __launch_bounds__(256, 2) void kconv(
    const int8_t* __restrict__ xp, const int8_t* __restrict__ aw,
    const float* __restrict__ am,       // [0..255]=alpha_w, [256..511]=mean_w
    const float* __restrict__ rs,       // [n][QP] row sums (for inline T)
    const float* __restrict__ bng, const float* __restrict__ bnb,
    const float* __restrict__ bnm, const float* __restrict__ bnv,
    const float* __restrict__ pos, const float* __restrict__ neg,
    const float* __restrict__ xT,       // EPI==1: residual, [n][PLN][c] f32
    const bf16* __restrict__ x1r,       // EPI==2: x1T [n][CCH][QO] bf16
    const float* __restrict__ a2, const float* __restrict__ b2,  // EPI==1
    int8_t* __restrict__ xpn,           // EPI==1: Xp2 interior (i8)
    bf16* __restrict__ x1t,             // EPI==1: x1T [n][CCH][QO] bf16
    float* __restrict__ rsn,            // EPI==1: rs2 accumulation (atomics)
    float* __restrict__ out)            // EPI==2: NCHW f32
{
  __shared__ char lds[73728];           // A 48KB (192*256) + B ring 3*8KB
  char* ldsB = lds + 49152;
  const int bid0 = blockIdx.x;
  const int bid = (bid0 & 7) * 112 + (bid0 >> 3);   // bijective XCD swizzle
  const int nt = bid & 1;
  const int mt = bid >> 1;
  const int n = mt / 7;
  const int qt = (mt % 7) * 128;
  const int o0 = nt * 128;
  const int t = threadIdx.x;
  const int lane = t & 63, wid = t >> 6;
  const int wp = (wid >> 1) * 64, wo = (wid & 1) * 64;

  // B staging decomposition (r7-proven)
  const int rowp = t >> 3;
  const int pcS = t & 7;
  const int cS = pcS ^ (rowp & 7);
  const int pS = cS >> 2;
  const int k16S = cS & 3;

  i32x4 acc[4][4];
#pragma unroll
  for (int i = 0; i < 4; ++i)
#pragma unroll
    for (int j = 0; j < 4; ++j) acc[i][j] = (i32x4){0, 0, 0, 0};

  const int r16 = lane & 15;
  const int g = lane >> 4;
  const int g4 = g * 4;
  const int rsh = r16 >> 1;
  const int pc0 = ((r16 & 1) * 4 + g) ^ rsh;   // B physical chunk for frag read
  const int wpH = (wid >> 1) * 32, woH = (wid & 1) * 32;
  // operand-block selection (the r8 bug fix):
  const int qoff = (EPI == 1) ? wp : wo;       // pixel-block offset (A region)
  const int ooffH = (EPI == 1) ? woH : wpH;    // weight LDS-row offset (B tile)

  const int8_t* baseB = aw + ((size_t)(o0 + 2 * rowp + pS)) * KTOT + k16S * 16;

  auto STAGE_B = [&](int buf, int ks) {
    const int8_t* sB = baseB + (size_t)ks * 64;
    char* dB = ldsB + buf * 8192;
    const int d0 = rowp * 128 + pcS * 16;
    gload_lds16(sB, dB + d0);
    gload_lds16(sB + (size_t)64 * KTOT, dB + 4096 + d0);
  };

  // ---- prologue: persistent A stage (190 rows x 16 chunks = 3040 tasks),
  // row-local chunk-XOR swizzle: LDS row rr, phys chunk pc holds global
  // chunk (pc ^ (rr&15)) of that row. LDS dest is linear task*16 per wave.
  {
    const int8_t* imgA = xp + ((size_t)(n * QP + qt)) * CCH;
#pragma unroll
    for (int i = 0; i < 12; ++i) {
      const int task = t + i * 256;
      if (task < 3040) {
        const int rr = task >> 4, pc = task & 15;
        gload_lds16(imgA + (size_t)rr * CCH + ((pc ^ (rr & 15)) * 16),
                    lds + rr * 256 + pc * 16);
      }
    }
  }
  STAGE_B(0, 0);
  STAGE_B(1, 1);
  asm volatile("s_waitcnt vmcnt(2)" ::: "memory");   // A + B0 complete
  __builtin_amdgcn_s_barrier();

#pragma unroll
  for (int ks = 0; ks < 36; ++ks) {
    const int tap = ks >> 2, ksl = ks & 3;
    const int shc = (tap / 3) * 30 + (tap % 3);
    const int cur = ks % 3;
    // A fragments: row ar = shc+qoff+idx*16+r16; logical chunk c = ksl*4+g,
    // physical = c ^ (ar&15) = c ^ ((r16+shc)&15)  (qoff, idx*16 ≡ 0 mod 16).
    const int achunk = ((ksl * 4 + g) ^ ((r16 + shc) & 15)) * 16;
    const char* pAr = lds + (shc + qoff + r16) * 256 + achunk;
    const char* pB = ldsB + cur * 8192;
    i32x4 fP[4], fW[4];
#pragma unroll
    for (int m = 0; m < 4; ++m) {
      fP[m] = *(const i32x4*)&pAr[m * 4096];
      fW[m] = *(const i32x4*)&pB[(ooffH + m * 8 + rsh) * 128 + pc0 * 16];
    }
    if (ks < 34) STAGE_B((ks + 2) % 3, ks + 2);
    __builtin_amdgcn_s_setprio(1);
    if constexpr (EPI == 1) {
      // D[q][o]: pixels are A-operand (rows), weights are B-operand (cols)
#pragma unroll
      for (int m = 0; m < 4; ++m)
#pragma unroll
        for (int nn = 0; nn < 4; ++nn)
          acc[m][nn] = __builtin_amdgcn_mfma_i32_16x16x64_i8(
              fP[m], fW[nn], acc[m][nn], 0, 0, 0);
    } else {
      // D[o][q]: weights are A-operand (rows, wp block), pixels B (wo block)
#pragma unroll
      for (int m = 0; m < 4; ++m)
#pragma unroll
        for (int nn = 0; nn < 4; ++nn)
          acc[m][nn] = __builtin_amdgcn_mfma_i32_16x16x64_i8(
              fW[m], fP[nn], acc[m][nn], 0, 0, 0);
    }
    __builtin_amdgcn_s_setprio(0);
    if (ks < 34) {
      asm volatile("s_waitcnt vmcnt(2)" ::: "memory");
    } else {
      asm volatile("s_waitcnt vmcnt(0)" ::: "memory");
    }
    __builtin_amdgcn_s_barrier();
  }

  if constexpr (EPI == 1) {
    // D[q = qt+wp+m*16+g4+r][o = o0+wo+nn*16+r16]
    int oc[4];
    float invc[4], addc[4], ppc[4], ngc[4], awc[4], mwc[4], aac[4], bbc[4];
#pragma unroll
    for (int nn = 0; nn < 4; ++nn) {
      const int o = o0 + wo + nn * 16 + r16;
      oc[nn] = o;
      const float inv = bng[o] / sqrtf(bnv[o] + 1e-5f);
      invc[nn] = inv;
      addc[nn] = bnb[o] - bnm[o] * inv;
      ppc[nn] = pos[o]; ngc[nn] = neg[o];
      awc[nn] = am[o];  mwc[nn] = am[CCH + o];
      aac[nn] = a2[o];  bbc[nn] = b2[o];
    }
    short* tb = (short*)lds;            // [128][136] transpose staging
#pragma unroll
    for (int m = 0; m < 4; ++m) {
#pragma unroll
      for (int r = 0; r < 4; ++r) {
        const int ql = wp + m * 16 + g4 + r;
        const int q = qt + ql;
        const int hh = q / 30, ww2 = q % 30;
        if (hh < HW && ww2 < HW) {      // uniform per 16-lane group
          const float* rrow = rs + (size_t)n * QP + q;
          float tq = 0.f;
#pragma unroll
          for (int kh = 0; kh < 3; ++kh)
#pragma unroll
            for (int kw = 0; kw < 3; ++kw) tq += rrow[kh * 30 + kw];
          const float* xrow = xT + ((size_t)n * PLN + hh * HW + ww2) * CCH;
          float rowsum = 0.f;
#pragma unroll
          for (int nn = 0; nn < 4; ++nn) {
            const int o = oc[nn];
            float v = awc[nn] * (float)acc[m][nn][r] + mwc[nn] * tq;
            v = v * invc[nn] + addc[nn];
            v += xrow[o];               // coalesced 64B per 16-group
            v = v > 0.f ? ppc[nn] * v : ngc[nn] * v;
            const float xa = (v - bbc[nn]) / aac[nn];
            const float sg = xa > 0.f ? 1.f : (xa < 0.f ? -1.f : 0.f);
            const float bv = sg * aac[nn] + bbc[nn];
            rowsum += bv;
            xpn[((size_t)n * QP + (hh + 1) * 30 + (ww2 + 1)) * CCH + o] =
                (int8_t)__float2int_rn(bv);
            bf16 hb = __float2bfloat16(v);
            tb[(wo + nn * 16 + r16) * 136 + ql] = *reinterpret_cast<short*>(&hb);
          }
          rowsum += __shfl_xor(rowsum, 8); rowsum += __shfl_xor(rowsum, 4);
          rowsum += __shfl_xor(rowsum, 2); rowsum += __shfl_xor(rowsum, 1);
          if (r16 == 0)
            atomicAdd(&rsn[(size_t)n * QP + (hh + 1) * 30 + (ww2 + 1)], rowsum);
        }
      }
    }
    __syncthreads();
    // transpose readout: x1T[n][o0+o_l][qt + half*64 ..] coalesced 16B
    {
      const int o_l = t >> 1, half = t & 1;
      short* x1s = (short*)x1t;
      const size_t gbase = ((size_t)(n * CCH + o0 + o_l)) * QO + qt + half * 64;
#pragma unroll
      for (int j = 0; j < 8; ++j)
        *(short8*)(x1s + gbase + j * 8) = *(const short8*)&tb[o_l * 136 + half * 64 + j * 8];
    }
  } else {
    // D[o = o0+wp+m*16+g4+r][q = qt+wo+nn*16+c16]
    float* cst = (float*)lds;           // [5][128] per-o fused constants
    if (t < 128) {
      const int o = o0 + t;
      const float inv = bng[o] / sqrtf(bnv[o] + 1e-5f);
      cst[t]       = am[o] * inv;           // alpha_w * inv
      cst[128 + t] = am[CCH + o] * inv;     // mean_w * inv
      cst[256 + t] = bnb[o] - bnm[o] * inv; // additive
      cst[384 + t] = pos[o];
      cst[512 + t] = neg[o];
    }
    __syncthreads();
    const int c16 = lane & 15;
#pragma unroll
    for (int nn = 0; nn < 4; ++nn) {
      const int q = qt + wo + nn * 16 + c16;
      const int hh = q / 30, ww2 = q % 30;
      const bool valid = (hh < HW) && (ww2 < HW);
      const float* rrow = rs + (size_t)n * QP + q;
      float tq = 0.f;
#pragma unroll
      for (int kh = 0; kh < 3; ++kh)
#pragma unroll
        for (int kw = 0; kw < 3; ++kw) tq += rrow[kh * 30 + kw];
#pragma unroll
      for (int m = 0; m < 4; ++m) {
#pragma unroll
        for (int r = 0; r < 4; ++r) {
          const int ol = wp + m * 16 + g4 + r;
          const int o = o0 + ol;
          if (valid) {
            float v = cst[ol] * (float)acc[m][nn][r] + cst[128 + ol] * tq + cst[256 + ol];
            v += __bfloat162float(x1r[((size_t)(n * CCH + o)) * QO + q]);
            v = v > 0.f ? cst[384 + ol] * v : cst[512 + ol] * v;
            out[((size_t)(n * CCH + o)) * PLN + hh * HW + ww2] = v;
          }
        }
      }
    }
  }
}

extern "C" void kernel_launch(void* const* d_in, const int* in_sizes, int n_in,
                              void* d_out, int out_size, void* d_ws, size_t ws_size,
                              hipStream_t stream) {
  const float* x   = (const float*)d_in[0];
  const float* w1  = (const float*)d_in[1];
  const float* al1 = (const float*)d_in[2];
  const float* be1 = (const float*)d_in[3];
  const float* g1  = (const float*)d_in[4];
  const float* bb1 = (const float*)d_in[5];
  const float* m1  = (const float*)d_in[6];
  const float* v1  = (const float*)d_in[7];
  const float* p1  = (const float*)d_in[8];
  const float* n1  = (const float*)d_in[9];
  const float* w2  = (const float*)d_in[10];
  const float* al2 = (const float*)d_in[11];
  const float* be2 = (const float*)d_in[12];
  const float* g2  = (const float*)d_in[13];
  const float* bb2 = (const float*)d_in[14];
  const float* m2  = (const float*)d_in[15];
  const float* v2  = (const float*)d_in[16];
  const float* p2  = (const float*)d_in[17];
  const float* n2  = (const float*)d_in[18];
  float* out = (float*)d_out;

  char* ws = (char*)d_ws;
  int8_t* Xp1 = (int8_t*)(ws);
  int8_t* Xp2 = (int8_t*)(ws + 15728640);
  bf16*   X1T = (bf16*)(ws + 31457280);
  int8_t* Aw1 = (int8_t*)(ws + 60817408);
  int8_t* Aw2 = (int8_t*)(ws + 61407232);
  float*  am1 = (float*)(ws + 61997056);
  float*  am2 = (float*)(ws + 61999104);
  float*  rs1 = (float*)(ws + 62001152);
  float*  rs2 = (float*)(ws + 62246912);
  float*  xT  = out;  // reused as scratch; kconv2 overwrites with final output

  kinit<<<248, 256, 0, stream>>>(Xp1, Xp2, (i32x4*)rs1);   // rs1+rs2 contiguous
  kwprep<<<512, 256, 0, stream>>>(w1, w2, Aw1, Aw2, am1, am2);
  kaprep<<<NIMG * HW, 256, 0, stream>>>(x, al1, be1, Xp1, rs1, xT);
  kconv<1><<<896, 256, 0, stream>>>(Xp1, Aw1, am1, rs1, g1, bb1, m1, v1, p1, n1,
                                    xT, nullptr, al2, be2, Xp2, X1T, rs2, nullptr);
  kconv<2><<<896, 256, 0, stream>>>(Xp2, Aw2, am2, rs2, g2, bb2, m2, v2, p2, n2,
                                    nullptr, X1T, nullptr, nullptr, nullptr, nullptr,
                                    nullptr, out);
}